// Round 3
// baseline (1456.376 us; speedup 1.0000x reference)
//
#include <hip/hip_runtime.h>

#define NN    100000   // nodes
#define NEDGE 100000   // edges per relation
#define NRELS 6
#define HIDD  256
#define NGR   128      // graphs
#define NKEY  (NRELS * NN)        // 600000 (rel,tgt) keys
#define NEDGT (NRELS * NEDGE)     // 600000 edges total
#define KTOT  (7 * HIDD)          // 1792: 6 rel segments + self segment

// old (fallback) GEMM tiling
#define BM 128
#define BN 64
#define BK 32
// new concat-GEMM tiling
#define BN2 128

typedef __bf16 bf16;
typedef __bf16 bf16x4 __attribute__((ext_vector_type(4)));
typedef __bf16 bf16x8 __attribute__((ext_vector_type(8)));
typedef float  f32x4  __attribute__((ext_vector_type(4)));
typedef unsigned int u32;

__device__ __forceinline__ void gl_lds16(const void* g, void* l) {
    __builtin_amdgcn_global_load_lds(
        (const __attribute__((address_space(1))) u32*)g,
        (__attribute__((address_space(3))) u32*)l, 16, 0, 0);
}

// ---------------- embed ----------------
__global__ __launch_bounds__(256)
void embed_kernel(const int* __restrict__ xt, const int* __restrict__ xs,
                  const float* __restrict__ temb, const float* __restrict__ semb,
                  bf16* __restrict__ h)
{
    int n = blockIdx.x;
    int f = threadIdx.x;
    float v;
    if (f < 128) v = temb[xt[n] * 128 + f];
    else         v = semb[xs[n] * 128 + (f - 128)];
    h[(size_t)n * HIDD + f] = (bf16)v;
}

// ================= CSR build =================
__global__ __launch_bounds__(256)
void hist_kernel(const int* __restrict__ edges, int* __restrict__ hist)
{
    int i = blockIdx.x * 256 + threadIdx.x;
    if (i >= NEDGT) return;
    int r = i / NEDGE;
    int e = i - r * NEDGE;
    int t = edges[r * (2 * NEDGE) + NEDGE + e];
    atomicAdd(&hist[r * NN + t], 1);
}

// level-0 scan: 2048 elems/block -> per-elem within-block exclusive + block sums
__global__ __launch_bounds__(256)
void scan_l0(const int* __restrict__ in, int* __restrict__ out, int* __restrict__ bsum, int n)
{
    __shared__ int sdata[256];
    const int t = threadIdx.x;
    const int base = blockIdx.x * 2048 + t * 8;
    int v[8]; int s = 0;
#pragma unroll
    for (int i = 0; i < 8; ++i) {
        int idx = base + i;
        int x = (idx < n) ? in[idx] : 0;
        v[i] = s; s += x;
    }
    sdata[t] = s;
    __syncthreads();
    for (int off = 1; off < 256; off <<= 1) {
        int y = (t >= off) ? sdata[t - off] : 0;
        __syncthreads();
        sdata[t] += y;
        __syncthreads();
    }
    int excl = sdata[t] - s;
#pragma unroll
    for (int i = 0; i < 8; ++i) {
        int idx = base + i;
        if (idx < n) out[idx] = excl + v[i];
    }
    if (t == 0) bsum[blockIdx.x] = sdata[255];
}

// level-1: single block, in-place exclusive scan of bsum (n <= 2048)
__global__ __launch_bounds__(256)
void scan_l1(int* __restrict__ bsum, int n)
{
    __shared__ int sdata[256];
    const int t = threadIdx.x;
    const int base = t * 8;
    int v[8]; int s = 0;
#pragma unroll
    for (int i = 0; i < 8; ++i) {
        int idx = base + i;
        int x = (idx < n) ? bsum[idx] : 0;
        v[i] = s; s += x;
    }
    sdata[t] = s;
    __syncthreads();
    for (int off = 1; off < 256; off <<= 1) {
        int y = (t >= off) ? sdata[t - off] : 0;
        __syncthreads();
        sdata[t] += y;
        __syncthreads();
    }
    int excl = sdata[t] - s;
#pragma unroll
    for (int i = 0; i < 8; ++i) {
        int idx = base + i;
        if (idx < n) bsum[idx] = excl + v[i];
    }
}

// level-2: add scanned block sums; also copy to cursor
__global__ __launch_bounds__(256)
void scan_l2(int* __restrict__ offs, int* __restrict__ cursor, const int* __restrict__ bsum, int n)
{
    int idx = blockIdx.x * 256 + threadIdx.x;
    if (idx >= n) return;
    int v = offs[idx] + bsum[idx >> 11];
    offs[idx] = v;
    cursor[idx] = v;
}

__global__ __launch_bounds__(256)
void scatter_kernel(const int* __restrict__ edges, int* __restrict__ cursor,
                    int* __restrict__ sorted_src)
{
    int i = blockIdx.x * 256 + threadIdx.x;
    if (i >= NEDGT) return;
    int r = i / NEDGE;
    int e = i - r * NEDGE;
    int s = edges[r * (2 * NEDGE) + e];
    int t = edges[r * (2 * NEDGE) + NEDGE + e];
    int pos = atomicAdd(&cursor[r * NN + t], 1);
    sorted_src[pos] = s;
}

__global__ __launch_bounds__(256)
void invdeg_kernel(const int* __restrict__ hist, float* __restrict__ invdeg)
{
    int t = blockIdx.x * 256 + threadIdx.x;
    if (t >= NN) return;
    int d = 0;
#pragma unroll
    for (int r = 0; r < NRELS; ++r) d += hist[r * NN + t];
    invdeg[t] = 1.0f / fmaxf((float)d, 1.0f);
}

// ---------------- aggregate: agg[key][:] = (sum h[src]) * invdeg[t], bf16 ----------------
__global__ __launch_bounds__(256)
void aggregate_kernel(const bf16* __restrict__ h, const int* __restrict__ offs,
                      const int* __restrict__ cursor, const int* __restrict__ sorted_src,
                      const float* __restrict__ invdeg, bf16* __restrict__ agg)
{
    int id = blockIdx.x * 4 + (threadIdx.x >> 6);
    if (id >= NKEY) return;
    const int lane = threadIdx.x & 63;
    const int start = offs[id];
    const int end   = cursor[id];   // == offs[id+1] after scatter
    const int t = id % NN;
    const float inv = invdeg[t];
    float a0 = 0, a1 = 0, a2 = 0, a3 = 0;
    const int f0 = lane * 4;
    for (int e = start; e < end; ++e) {
        int s = sorted_src[e];
        bf16x4 u = *(const bf16x4*)(h + (size_t)s * HIDD + f0);
        a0 += (float)u.x; a1 += (float)u.y; a2 += (float)u.z; a3 += (float)u.w;
    }
    bf16x4 o;
    o.x = (bf16)(a0 * inv); o.y = (bf16)(a1 * inv);
    o.z = (bf16)(a2 * inv); o.w = (bf16)(a3 * inv);
    *(bf16x4*)(agg + (size_t)id * HIDD + f0) = o;
}

// ---------------- Wcat[n][r*256+k] = W_rel[r][k][n]; seg 6 = W_self[k][n] ----------------
// grid (7, 256): blockIdx.x = seg, blockIdx.y = k, thread = n (coalesced read)
__global__ __launch_bounds__(256)
void build_wcat(const float* __restrict__ Wrel, const float* __restrict__ Wself,
                bf16* __restrict__ Wcat)
{
    int seg = blockIdx.x;
    int k = blockIdx.y;
    int n = threadIdx.x;
    float v = (seg < 6) ? Wrel[((size_t)seg << 16) + (k << 8) + n] : Wself[(k << 8) + n];
    Wcat[(size_t)n * KTOT + seg * 256 + k] = (bf16)v;
}

// ---------------- concat GEMM: out[t] = relu([agg|h][t] @ Wcat^T + b), bf16 out ----------------
// grid (2, ceil(NN/128)), block 256 = 4 waves; wave w: rows w*32..w*32+31, cols n0..n0+127
// LDS layout (k-chunk-major groups, matches global_load_lds lane*16 placement):
//   A group g (16 rows), chunk c (8 k), f (row in group): elem offset g*512 + c*128 + f*8
__global__ __launch_bounds__(256, 2)
void gemm_cat(const bf16* __restrict__ agg, const bf16* __restrict__ h,
              const bf16* __restrict__ Wcat, const float* __restrict__ bias,
              bf16* __restrict__ outbf)
{
    const int m0 = blockIdx.y * BM;
    const int n0 = blockIdx.x * BN2;

    __shared__ __align__(16) bf16 As[BM * BK];   // 8 KB
    __shared__ __align__(16) bf16 Bs[BN2 * BK];  // 8 KB

    const int tid = threadIdx.x, lane = tid & 63, w = tid >> 6;

    // staging row/col per thread (two passes: +0 rows 0-63 groups, +64)
    const int srow = (tid >> 6) * 16 + (tid & 15);      // row within tile, pass 0
    const int scol = ((tid >> 4) & 3) * 8;              // k offset (chunk*8)
    int mA0 = m0 + srow;       if (mA0 >= NN) mA0 = NN - 1;
    int mA1 = m0 + srow + 64;  if (mA1 >= NN) mA1 = NN - 1;
    const bf16* const brow0 = Wcat + (size_t)(n0 + srow) * KTOT + scol;
    const bf16* const brow1 = Wcat + (size_t)(n0 + srow + 64) * KTOT + scol;

    const int fm = lane & 15;
    const int fq = lane >> 4;           // k-chunk 0..3

    f32x4 acc[2][8] = {};

    for (int k0 = 0; k0 < KTOT; k0 += BK) {
        const int seg = k0 >> 8;
        const int koff = (k0 & 255) + scol;
        const bf16* asrc0 = (seg < 6) ? agg + (((size_t)seg * NN + mA0) << 8) + koff
                                      : h + ((size_t)mA0 << 8) + koff;
        const bf16* asrc1 = (seg < 6) ? agg + (((size_t)seg * NN + mA1) << 8) + koff
                                      : h + ((size_t)mA1 << 8) + koff;
        gl_lds16(asrc0,     &As[tid * 8]);
        gl_lds16(asrc1,     &As[tid * 8 + 2048]);
        gl_lds16(brow0 + k0, &Bs[tid * 8]);
        gl_lds16(brow1 + k0, &Bs[tid * 8 + 2048]);
        __syncthreads();   // drains vmcnt before barrier (compiler-inserted)

        bf16x8 af[2], bfr[8];
        af[0] = *(const bf16x8*)&As[w * 1024 + fq * 128 + fm * 8];
        af[1] = *(const bf16x8*)&As[w * 1024 + 512 + fq * 128 + fm * 8];
#pragma unroll
        for (int j = 0; j < 8; ++j)
            bfr[j] = *(const bf16x8*)&Bs[j * 512 + fq * 128 + fm * 8];
#pragma unroll
        for (int i = 0; i < 2; ++i)
#pragma unroll
            for (int j = 0; j < 8; ++j)
                acc[i][j] = __builtin_amdgcn_mfma_f32_16x16x32_bf16(af[i], bfr[j], acc[i][j], 0, 0, 0);
        __syncthreads();
    }

    // epilogue: C row = w*32 + i*16 + fq*4 + reg, col = n0 + j*16 + fm
    float bv[8];
#pragma unroll
    for (int j = 0; j < 8; ++j) bv[j] = bias[n0 + j * 16 + fm];
    const int rbase = fq * 4;
#pragma unroll
    for (int i = 0; i < 2; ++i) {
#pragma unroll
        for (int reg = 0; reg < 4; ++reg) {
            int row = m0 + w * 32 + i * 16 + rbase + reg;
            if (row < NN) {
                bf16* po = outbf + ((size_t)row << 8) + n0 + fm;
#pragma unroll
                for (int j = 0; j < 8; ++j)
                    po[j * 16] = (bf16)fmaxf(acc[i][j][reg] + bv[j], 0.0f);
            }
        }
    }
}

// ================= fallback (round-2) kernels =================
__global__ __launch_bounds__(256)
void deg_kernel(const int* __restrict__ edges, float* __restrict__ deg)
{
    int i = blockIdx.x * 256 + threadIdx.x;
    if (i >= NEDGT) return;
    int r = i / NEDGE;
    int e = i - r * NEDGE;
    int t = edges[r * (2 * NEDGE) + NEDGE + e];
    atomicAdd(&deg[t], 1.0f);
}

__global__ __launch_bounds__(256)
void transpose_w(const float* __restrict__ W, bf16* __restrict__ Wt)
{
    int idx = blockIdx.x * 256 + threadIdx.x;
    int r = idx >> 16;
    int n = (idx >> 8) & 255;
    int k = idx & 255;
    Wt[((size_t)r << 16) + (n << 8) + k] = (bf16)W[((size_t)r << 16) + (k << 8) + n];
}

__global__ __launch_bounds__(256, 2)
void rel_gemm_mfma(const bf16* __restrict__ hbf, const bf16* __restrict__ Wt,
                   const int* __restrict__ edges, float* __restrict__ accum)
{
    const int r = blockIdx.z;
    const bf16* __restrict__ W = Wt + ((size_t)r << 16);
    const int* __restrict__ src = edges + (size_t)r * 2 * NEDGE;
    const int* __restrict__ tgt = src + NEDGE;
    const int m0 = blockIdx.x * BM;
    const int n0 = blockIdx.y * BN;

    __shared__ __align__(16) bf16 As[BM * BK];
    __shared__ __align__(16) bf16 Bs[BN * BK];
    __shared__ int src_l[BM];
    __shared__ int tgt_l[BM];

    const int tid = threadIdx.x;
    if (tid < BM) {
        int e = m0 + tid;
        int s = 0, t = -1;
        if (e < NEDGE) { s = src[e]; t = tgt[e]; }
        src_l[tid] = s; tgt_l[tid] = t;
    }
    __syncthreads();

    const int lane = tid & 63;
    const int w = tid >> 6;
    const int arow0 = tid >> 2;
    const int acol  = (tid & 3) * 8;
    const size_t ga0 = (size_t)src_l[arow0] * HIDD + acol;
    const size_t ga1 = (size_t)src_l[arow0 + 64] * HIDD + acol;
    const bf16* __restrict__ bsrc = W + (size_t)(n0 + arow0) * HIDD + acol;
    const int fm = lane & 15;
    const int kq = (lane >> 4) * 8;

    f32x4 acc[2][4] = {};
    for (int k0 = 0; k0 < HIDD; k0 += BK) {
        uint4 a0 = *(const uint4*)(hbf + ga0 + k0);
        uint4 a1 = *(const uint4*)(hbf + ga1 + k0);
        uint4 b0 = *(const uint4*)(bsrc + k0);
        __syncthreads();
        *(uint4*)&As[arow0 * BK + acol]        = a0;
        *(uint4*)&As[(arow0 + 64) * BK + acol] = a1;
        *(uint4*)&Bs[arow0 * BK + acol]        = b0;
        __syncthreads();
        bf16x8 af[2], bfr[4];
        af[0] = *(const bf16x8*)&As[(w * 32 + fm) * BK + kq];
        af[1] = *(const bf16x8*)&As[(w * 32 + 16 + fm) * BK + kq];
#pragma unroll
        for (int j = 0; j < 4; ++j)
            bfr[j] = *(const bf16x8*)&Bs[(j * 16 + fm) * BK + kq];
#pragma unroll
        for (int i = 0; i < 2; ++i)
#pragma unroll
            for (int j = 0; j < 4; ++j)
                acc[i][j] = __builtin_amdgcn_mfma_f32_16x16x32_bf16(af[i], bfr[j], acc[i][j], 0, 0, 0);
    }
    const int rbase = (lane >> 4) * 4;
#pragma unroll
    for (int i = 0; i < 2; ++i) {
#pragma unroll
        for (int reg = 0; reg < 4; ++reg) {
            int mrow = w * 32 + i * 16 + rbase + reg;
            int t = tgt_l[mrow];
            if (t >= 0) {
                float* dst = accum + (size_t)t * HIDD + n0 + fm;
#pragma unroll
                for (int j = 0; j < 4; ++j)
                    atomicAdd(dst + j * 16, acc[i][j][reg]);
            }
        }
    }
}

__global__ __launch_bounds__(256, 2)
void self_gemm_mfma(const bf16* __restrict__ hbf, const bf16* __restrict__ Wt,
                    const float* __restrict__ bias, const float* __restrict__ deg,
                    const float* __restrict__ accum, bf16* __restrict__ outbf)
{
    const int m0 = blockIdx.x * BM;
    const int n0 = blockIdx.y * BN;
    __shared__ __align__(16) bf16 As[BM * BK];
    __shared__ __align__(16) bf16 Bs[BN * BK];
    const int tid = threadIdx.x;
    const int lane = tid & 63;
    const int w = tid >> 6;
    const int arow0 = tid >> 2;
    const int acol  = (tid & 3) * 8;
    int r0 = m0 + arow0;      if (r0 >= NN) r0 = NN - 1;
    int r1 = m0 + arow0 + 64; if (r1 >= NN) r1 = NN - 1;
    const size_t ga0 = (size_t)r0 * HIDD + acol;
    const size_t ga1 = (size_t)r1 * HIDD + acol;
    const bf16* __restrict__ bsrc = Wt + (size_t)(n0 + arow0) * HIDD + acol;
    const int fm = lane & 15;
    const int kq = (lane >> 4) * 8;
    f32x4 acc[2][4] = {};
    for (int k0 = 0; k0 < HIDD; k0 += BK) {
        uint4 a0 = *(const uint4*)(hbf + ga0 + k0);
        uint4 a1 = *(const uint4*)(hbf + ga1 + k0);
        uint4 b0 = *(const uint4*)(bsrc + k0);
        __syncthreads();
        *(uint4*)&As[arow0 * BK + acol]        = a0;
        *(uint4*)&As[(arow0 + 64) * BK + acol] = a1;
        *(uint4*)&Bs[arow0 * BK + acol]        = b0;
        __syncthreads();
        bf16x8 af[2], bfr[4];
        af[0] = *(const bf16x8*)&As[(w * 32 + fm) * BK + kq];
        af[1] = *(const bf16x8*)&As[(w * 32 + 16 + fm) * BK + kq];
#pragma unroll
        for (int j = 0; j < 4; ++j)
            bfr[j] = *(const bf16x8*)&Bs[(j * 16 + fm) * BK + kq];
#pragma unroll
        for (int i = 0; i < 2; ++i)
#pragma unroll
            for (int j = 0; j < 4; ++j)
                acc[i][j] = __builtin_amdgcn_mfma_f32_16x16x32_bf16(af[i], bfr[j], acc[i][j], 0, 0, 0);
    }
    const int rbase = (lane >> 4) * 4;
#pragma unroll
    for (int i = 0; i < 2; ++i) {
#pragma unroll
        for (int reg = 0; reg < 4; ++reg) {
            int row = m0 + w * 32 + i * 16 + rbase + reg;
            if (row < NN) {
                float d = fmaxf(deg[row], 1.0f);
                float inv = 1.0f / d;
                const float* pa = accum + (size_t)row * HIDD + n0 + fm;
                bf16* po = outbf + (size_t)row * HIDD + n0 + fm;
#pragma unroll
                for (int j = 0; j < 4; ++j) {
                    float v = pa[j * 16] * inv + acc[i][j][reg] + bias[n0 + fm + j * 16];
                    po[j * 16] = (bf16)fmaxf(v, 0.0f);
                }
            }
        }
    }
}

// ---------------- pool + MLP ----------------
#define PCHUNK 512
__global__ __launch_bounds__(256)
void pool_kernel(const bf16* __restrict__ h, const int* __restrict__ batch_ids,
                 float* __restrict__ pooled, float* __restrict__ cnt)
{
    const int n0 = blockIdx.x * PCHUNK;
    const int f = threadIdx.x;
    __shared__ int bid_l[PCHUNK];
    for (int i = f; i < PCHUNK; i += 256) {
        int n = n0 + i;
        bid_l[i] = (n < NN) ? batch_ids[n] : -1;
    }
    __syncthreads();
    const int nEnd = (NN - n0 < PCHUNK) ? (NN - n0) : PCHUNK;
    float s = 0.0f;
    int g = bid_l[0];
    int run = 0;
    for (int i = 0; i < nEnd; ++i) {
        int bg = bid_l[i];
        if (bg != g) {
            atomicAdd(&pooled[g * HIDD + f], s);
            if (f == 0) atomicAdd(&cnt[g], (float)run);
            s = 0.0f; run = 0; g = bg;
        }
        s += (float)h[(size_t)(n0 + i) * HIDD + f];
        run++;
    }
    if (run > 0) {
        atomicAdd(&pooled[g * HIDD + f], s);
        if (f == 0) atomicAdd(&cnt[g], (float)run);
    }
}

__global__ __launch_bounds__(256)
void mlp_kernel(const float* __restrict__ pooled, const float* __restrict__ cnt,
                const float* __restrict__ pW1, const float* __restrict__ pb1,
                const float* __restrict__ pW2, const float* __restrict__ pb2,
                float* __restrict__ out)
{
    const int g = blockIdx.x;
    const int d = threadIdx.x;
    __shared__ float pn[HIDD];
    __shared__ float mid[HIDD];
    float c = fmaxf(cnt[g], 1.0f);
    pn[d] = pooled[g * HIDD + d] / c;
    __syncthreads();
    float s = pb1[d];
    for (int k = 0; k < HIDD; ++k) s = fmaf(pn[k], pW1[k * HIDD + d], s);
    mid[d] = fmaxf(s, 0.0f);
    __syncthreads();
    float s2 = pb2[d];
    for (int k = 0; k < HIDD; ++k) s2 = fmaf(mid[k], pW2[k * HIDD + d], s2);
    out[g * HIDD + d] = s2;
}

extern "C" void kernel_launch(void* const* d_in, const int* in_sizes, int n_in,
                              void* d_out, int out_size, void* d_ws, size_t ws_size,
                              hipStream_t stream)
{
    const int*   x_type    = (const int*)d_in[0];
    const int*   x_sub     = (const int*)d_in[1];
    const int*   edges     = (const int*)d_in[2];
    const int*   batch_ids = (const int*)d_in[3];
    const float* type_emb  = (const float*)d_in[5];
    const float* sub_emb   = (const float*)d_in[6];
    const float* W_rel0    = (const float*)d_in[7];
    const float* W_self0   = (const float*)d_in[8];
    const float* b0        = (const float*)d_in[9];
    const float* W_rel1    = (const float*)d_in[10];
    const float* W_self1   = (const float*)d_in[11];
    const float* b1        = (const float*)d_in[12];
    const float* pW1       = (const float*)d_in[13];
    const float* pb1       = (const float*)d_in[14];
    const float* pW2       = (const float*)d_in[15];
    const float* pb2       = (const float*)d_in[16];
    float* out = (float*)d_out;

    const size_t NEED_NEW = 426000000ull;   // ~406 MiB

    if (ws_size >= NEED_NEW) {
        // ===== CSR + concat-GEMM path =====
        char* p = (char*)d_ws;
        auto carve = [&](size_t bytes) { char* q = p; p += (bytes + 255) & ~255ull; return q; };
        bf16*  agg    = (bf16*) carve((size_t)NKEY * HIDD * sizeof(bf16));   // 307.2 MB
        bf16*  hA     = (bf16*) carve((size_t)NN * HIDD * sizeof(bf16));
        bf16*  hB     = (bf16*) carve((size_t)NN * HIDD * sizeof(bf16));
        bf16*  Wcat0  = (bf16*) carve((size_t)HIDD * KTOT * sizeof(bf16));
        bf16*  Wcat1  = (bf16*) carve((size_t)HIDD * KTOT * sizeof(bf16));
        float* invdeg = (float*)carve((size_t)NN * sizeof(float));
        int*   hist   = (int*)  carve((size_t)NKEY * sizeof(int));
        int*   offs   = (int*)  carve((size_t)(NKEY + 1) * sizeof(int));
        int*   cursor = (int*)  carve((size_t)NKEY * sizeof(int));
        int*   bsum   = (int*)  carve(2048 * sizeof(int));
        int*   ssrc   = (int*)  carve((size_t)NEDGT * sizeof(int));
        float* pooled = (float*)carve((size_t)NGR * HIDD * sizeof(float));
        float* cnt    = (float*)carve((size_t)NGR * sizeof(float));

        hipMemsetAsync(hist, 0, (size_t)NKEY * sizeof(int), stream);
        hipMemsetAsync(pooled, 0, (size_t)NGR * (HIDD + 1) * sizeof(float), stream);
        // (pooled and cnt are adjacent carves; clear both regions explicitly)
        hipMemsetAsync(cnt, 0, (size_t)NGR * sizeof(float), stream);

        embed_kernel<<<NN, 256, 0, stream>>>(x_type, x_sub, type_emb, sub_emb, hA);

        const int NB0 = (NKEY + 2047) / 2048;  // 293
        hist_kernel<<<(NEDGT + 255) / 256, 256, 0, stream>>>(edges, hist);
        scan_l0<<<NB0, 256, 0, stream>>>(hist, offs, bsum, NKEY);
        scan_l1<<<1, 256, 0, stream>>>(bsum, NB0);
        scan_l2<<<(NKEY + 255) / 256, 256, 0, stream>>>(offs, cursor, bsum, NKEY);
        scatter_kernel<<<(NEDGT + 255) / 256, 256, 0, stream>>>(edges, cursor, ssrc);
        invdeg_kernel<<<(NN + 255) / 256, 256, 0, stream>>>(hist, invdeg);

        dim3 wgrid(7, 256);
        build_wcat<<<wgrid, 256, 0, stream>>>(W_rel0, W_self0, Wcat0);
        build_wcat<<<wgrid, 256, 0, stream>>>(W_rel1, W_self1, Wcat1);

        dim3 ggrid(HIDD / BN2, (NN + BM - 1) / BM);
        const int AGG_BLOCKS = (NKEY + 3) / 4;

        // layer 0: hA -> hB
        aggregate_kernel<<<AGG_BLOCKS, 256, 0, stream>>>(hA, offs, cursor, ssrc, invdeg, agg);
        gemm_cat<<<ggrid, 256, 0, stream>>>(agg, hA, Wcat0, b0, hB);
        // layer 1: hB -> hA
        aggregate_kernel<<<AGG_BLOCKS, 256, 0, stream>>>(hB, offs, cursor, ssrc, invdeg, agg);
        gemm_cat<<<ggrid, 256, 0, stream>>>(agg, hB, Wcat1, b1, hA);

        pool_kernel<<<(NN + PCHUNK - 1) / PCHUNK, 256, 0, stream>>>(hA, batch_ids, pooled, cnt);
        mlp_kernel<<<NGR, 256, 0, stream>>>(pooled, cnt, pW1, pb1, pW2, pb2, out);
    } else {
        // ===== fallback: round-2 atomic-scatter path =====
        char* p = (char*)d_ws;
        float* accum   = (float*)p;  p += (size_t)NN * HIDD * sizeof(float);
        bf16*  hA      = (bf16*)p;   p += (size_t)NN * HIDD * sizeof(bf16);
        bf16*  hB      = (bf16*)p;   p += (size_t)NN * HIDD * sizeof(bf16);
        float* deg     = (float*)p;  p += (size_t)NN * sizeof(float);
        float* pooled  = (float*)p;  p += (size_t)NGR * HIDD * sizeof(float);
        float* cnt     = (float*)p;  p += (size_t)NGR * sizeof(float);
        bf16*  WtR0    = (bf16*)p;   p += (size_t)NRELS * HIDD * HIDD * sizeof(bf16);
        bf16*  WtR1    = (bf16*)p;   p += (size_t)NRELS * HIDD * HIDD * sizeof(bf16);
        bf16*  WtS0    = (bf16*)p;   p += (size_t)HIDD * HIDD * sizeof(bf16);
        bf16*  WtS1    = (bf16*)p;   p += (size_t)HIDD * HIDD * sizeof(bf16);

        hipMemsetAsync(deg, 0, (size_t)(NN + NGR * HIDD + NGR) * sizeof(float), stream);
        embed_kernel<<<NN, 256, 0, stream>>>(x_type, x_sub, type_emb, sub_emb, hA);
        deg_kernel<<<(NEDGT + 255) / 256, 256, 0, stream>>>(edges, deg);
        transpose_w<<<NRELS * 256, 256, 0, stream>>>(W_rel0, WtR0);
        transpose_w<<<NRELS * 256, 256, 0, stream>>>(W_rel1, WtR1);
        transpose_w<<<256, 256, 0, stream>>>(W_self0, WtS0);
        transpose_w<<<256, 256, 0, stream>>>(W_self1, WtS1);

        dim3 relgrid((NEDGE + BM - 1) / BM, HIDD / BN, NRELS);
        dim3 selfgrid((NN + BM - 1) / BM, HIDD / BN);

        hipMemsetAsync(accum, 0, (size_t)NN * HIDD * sizeof(float), stream);
        rel_gemm_mfma<<<relgrid, 256, 0, stream>>>(hA, WtR0, edges, accum);
        self_gemm_mfma<<<selfgrid, 256, 0, stream>>>(hA, WtS0, b0, deg, accum, hB);

        hipMemsetAsync(accum, 0, (size_t)NN * HIDD * sizeof(float), stream);
        rel_gemm_mfma<<<relgrid, 256, 0, stream>>>(hB, WtR1, edges, accum);
        self_gemm_mfma<<<selfgrid, 256, 0, stream>>>(hB, WtS1, b1, deg, accum, hA);

        pool_kernel<<<(NN + PCHUNK - 1) / PCHUNK, 256, 0, stream>>>(hA, batch_ids, pooled, cnt);
        mlp_kernel<<<NGR, 256, 0, stream>>>(pooled, cnt, pW1, pb1, pW2, pb2, out);
    }
}

// Round 4
// 1132.194 us; speedup vs baseline: 1.2863x; 1.2863x over previous
//
#include <hip/hip_runtime.h>

#define NN    100000   // nodes
#define NEDGE 100000   // edges per relation
#define NRELS 6
#define HIDD  256
#define NGR   128      // graphs
#define NKEY  (NRELS * NN)        // 600000 (rel,tgt) keys
#define NEDGT (NRELS * NEDGE)     // 600000 edges total
#define KTOT  (7 * HIDD)          // 1792

#define FBM 64                    // rows per block (nodes)

typedef __bf16 bf16;
typedef __bf16 bf16x4 __attribute__((ext_vector_type(4)));
typedef __bf16 bf16x8 __attribute__((ext_vector_type(8)));
typedef float  f32x16 __attribute__((ext_vector_type(16)));

// ---------------- embed ----------------
__global__ __launch_bounds__(256)
void embed_kernel(const int* __restrict__ xt, const int* __restrict__ xs,
                  const float* __restrict__ temb, const float* __restrict__ semb,
                  bf16* __restrict__ h)
{
    int n = blockIdx.x;
    int f = threadIdx.x;
    float v;
    if (f < 128) v = temb[xt[n] * 128 + f];
    else         v = semb[xs[n] * 128 + (f - 128)];
    h[(size_t)n * HIDD + f] = (bf16)v;
}

// ================= CSR build (key = rel*NN + tgt) =================
__global__ __launch_bounds__(256)
void hist_kernel(const int* __restrict__ edges, int* __restrict__ hist)
{
    int i = blockIdx.x * 256 + threadIdx.x;
    if (i >= NEDGT) return;
    int r = i / NEDGE;
    int e = i - r * NEDGE;
    int t = edges[r * (2 * NEDGE) + NEDGE + e];
    atomicAdd(&hist[r * NN + t], 1);
}

__global__ __launch_bounds__(256)
void scan_l0(const int* __restrict__ in, int* __restrict__ out, int* __restrict__ bsum, int n)
{
    __shared__ int sdata[256];
    const int t = threadIdx.x;
    const int base = blockIdx.x * 2048 + t * 8;
    int v[8]; int s = 0;
#pragma unroll
    for (int i = 0; i < 8; ++i) {
        int idx = base + i;
        int x = (idx < n) ? in[idx] : 0;
        v[i] = s; s += x;
    }
    sdata[t] = s;
    __syncthreads();
    for (int off = 1; off < 256; off <<= 1) {
        int y = (t >= off) ? sdata[t - off] : 0;
        __syncthreads();
        sdata[t] += y;
        __syncthreads();
    }
    int excl = sdata[t] - s;
#pragma unroll
    for (int i = 0; i < 8; ++i) {
        int idx = base + i;
        if (idx < n) out[idx] = excl + v[i];
    }
    if (t == 0) bsum[blockIdx.x] = sdata[255];
}

__global__ __launch_bounds__(256)
void scan_l1(int* __restrict__ bsum, int n)
{
    __shared__ int sdata[256];
    const int t = threadIdx.x;
    const int base = t * 8;
    int v[8]; int s = 0;
#pragma unroll
    for (int i = 0; i < 8; ++i) {
        int idx = base + i;
        int x = (idx < n) ? bsum[idx] : 0;
        v[i] = s; s += x;
    }
    sdata[t] = s;
    __syncthreads();
    for (int off = 1; off < 256; off <<= 1) {
        int y = (t >= off) ? sdata[t - off] : 0;
        __syncthreads();
        sdata[t] += y;
        __syncthreads();
    }
    int excl = sdata[t] - s;
#pragma unroll
    for (int i = 0; i < 8; ++i) {
        int idx = base + i;
        if (idx < n) bsum[idx] = excl + v[i];
    }
}

__global__ __launch_bounds__(256)
void scan_l2(int* __restrict__ offs, int* __restrict__ cursor, const int* __restrict__ bsum, int n)
{
    int idx = blockIdx.x * 256 + threadIdx.x;
    if (idx >= n) return;
    int v = offs[idx] + bsum[idx >> 11];
    offs[idx] = v;
    cursor[idx] = v;
}

__global__ __launch_bounds__(256)
void scatter_kernel(const int* __restrict__ edges, int* __restrict__ cursor,
                    int* __restrict__ sorted_src)
{
    int i = blockIdx.x * 256 + threadIdx.x;
    if (i >= NEDGT) return;
    int r = i / NEDGE;
    int e = i - r * NEDGE;
    int s = edges[r * (2 * NEDGE) + e];
    int t = edges[r * (2 * NEDGE) + NEDGE + e];
    int pos = atomicAdd(&cursor[r * NN + t], 1);
    sorted_src[pos] = s;
}

__global__ __launch_bounds__(256)
void invdeg_kernel(const int* __restrict__ hist, float* __restrict__ invdeg)
{
    int t = blockIdx.x * 256 + threadIdx.x;
    if (t >= NN) return;
    int d = 0;
#pragma unroll
    for (int r = 0; r < NRELS; ++r) d += hist[r * NN + t];
    invdeg[t] = 1.0f / fmaxf((float)d, 1.0f);
}

// ---------------- Wcat[n][seg*256+k]: seg<6 -> W_rel[seg][k][n], seg6 -> W_self[k][n] ----------------
__global__ __launch_bounds__(256)
void build_wcat(const float* __restrict__ Wrel, const float* __restrict__ Wself,
                bf16* __restrict__ Wcat)
{
    int seg = blockIdx.x;
    int k = blockIdx.y;
    int n = threadIdx.x;
    float v = (seg < 6) ? Wrel[((size_t)seg << 16) + (k << 8) + n] : Wself[(k << 8) + n];
    Wcat[(size_t)n * KTOT + seg * 256 + k] = (bf16)v;
}

// ---------------- fused RGCN layer: out[t] = relu(sum_seg A_seg[t] @ Wcat_seg^T + b) ----------------
// grid: ceil(NN/64) blocks, 256 threads (4 waves). Wave w: cols w*64..w*64+63, all 64 rows.
// LDS: As 64x256 bf16 (32 KB, XOR-swizzled 16B units), Bs 256x32 bf16 per chunk (16 KB, swizzled).
__global__ __launch_bounds__(256, 3)
void rgcn_fused(const bf16* __restrict__ hin, const bf16* __restrict__ Wcat,
                const float* __restrict__ bias, const float* __restrict__ invdeg,
                const int* __restrict__ offs, const int* __restrict__ cursor,
                const int* __restrict__ ssrc, bf16* __restrict__ hout)
{
    const int m0 = blockIdx.x * FBM;
    const int tid = threadIdx.x;
    const int lane = tid & 63;
    const int w = tid >> 6;

    __shared__ __align__(16) bf16 As[FBM * HIDD];   // 32 KB
    __shared__ __align__(16) bf16 Bs[HIDD * 32];    // 16 KB

    f32x16 acc[2][2] = {};

    const int l31 = lane & 31;
    const int lhi = lane >> 5;         // 0/1: k-octet within 16-k step
    const int kg_w = lane >> 1;        // agg write k-group (0..31)
    const int half = lane & 1;

    for (int seg = 0; seg < 7; ++seg) {
        __syncthreads();   // prior seg's MFMA reads of As done
        // ---- build As rows w*16 .. w*16+15 for this segment ----
        for (int r = 0; r < 16; ++r) {
            const int rw = w * 16 + r;
            const int gm = m0 + rw;
            float a0 = 0.f, a1 = 0.f, a2 = 0.f, a3 = 0.f;
            if (gm < NN) {
                if (seg < 6) {
                    const int id = seg * NN + gm;
                    const int st = offs[id];
                    const int en = cursor[id];
                    const float inv = invdeg[gm];
                    for (int e = st; e < en; ++e) {
                        const int s = ssrc[e];
                        bf16x4 u = *(const bf16x4*)(hin + ((size_t)s << 8) + (lane << 2));
                        a0 += (float)u.x; a1 += (float)u.y; a2 += (float)u.z; a3 += (float)u.w;
                    }
                    a0 *= inv; a1 *= inv; a2 *= inv; a3 *= inv;
                } else {
                    bf16x4 u = *(const bf16x4*)(hin + ((size_t)gm << 8) + (lane << 2));
                    a0 = (float)u.x; a1 = (float)u.y; a2 = (float)u.z; a3 = (float)u.w;
                }
            }
            bf16x4 o; o.x = (bf16)a0; o.y = (bf16)a1; o.z = (bf16)a2; o.w = (bf16)a3;
            const int unit = rw * 32 + (kg_w ^ (rw & 7));
            *(bf16x4*)&As[unit * 8 + half * 4] = o;
        }

        // ---- MFMA over 8 k-chunks of 32 ----
        for (int kc = 0; kc < 8; ++kc) {
            __syncthreads();   // As ready (kc==0) / prev chunk's Bs reads done
            // stage Bs: 256 cols x 32 k from Wcat
#pragma unroll
            for (int p = 0; p < 4; ++p) {
                const int flat = p * 256 + tid;
                const int n = flat >> 2;
                const int kg = flat & 3;
                bf16x8 v = *(const bf16x8*)(Wcat + (size_t)n * KTOT + seg * 256 + kc * 32 + kg * 8);
                const int unit = n * 4 + ((kg + (n >> 1)) & 3);
                *(bf16x8*)&Bs[unit * 8] = v;
            }
            __syncthreads();
#pragma unroll
            for (int ks = 0; ks < 2; ++ks) {
                const int kg = ks * 2 + lhi;          // 0..3 within chunk
                const int kl = kc * 4 + kg;           // 0..31 within seg
                bf16x8 afr[2], bfr[2];
#pragma unroll
                for (int rt = 0; rt < 2; ++rt) {
                    const int row = rt * 32 + l31;
                    const int u = row * 32 + (kl ^ (row & 7));
                    afr[rt] = *(const bf16x8*)&As[u * 8];
                }
#pragma unroll
                for (int ct = 0; ct < 2; ++ct) {
                    const int col = w * 64 + ct * 32 + l31;
                    const int u = col * 4 + ((kg + (col >> 1)) & 3);
                    bfr[ct] = *(const bf16x8*)&Bs[u * 8];
                }
#pragma unroll
                for (int rt = 0; rt < 2; ++rt)
#pragma unroll
                    for (int ct = 0; ct < 2; ++ct)
                        acc[rt][ct] = __builtin_amdgcn_mfma_f32_32x32x16_bf16(afr[rt], bfr[ct], acc[rt][ct], 0, 0, 0);
            }
        }
    }

    // ---- epilogue: C col = lane&31, row = (reg&3) + 8*(reg>>2) + 4*(lane>>5) ----
    float bcol[2];
#pragma unroll
    for (int ct = 0; ct < 2; ++ct) bcol[ct] = bias[w * 64 + ct * 32 + l31];
#pragma unroll
    for (int rt = 0; rt < 2; ++rt) {
#pragma unroll
        for (int reg = 0; reg < 16; ++reg) {
            const int row = m0 + rt * 32 + (reg & 3) + 8 * (reg >> 2) + 4 * lhi;
            if (row < NN) {
#pragma unroll
                for (int ct = 0; ct < 2; ++ct) {
                    const int col = w * 64 + ct * 32 + l31;
                    float v = acc[rt][ct][reg] + bcol[ct];
                    hout[((size_t)row << 8) + col] = (bf16)fmaxf(v, 0.0f);
                }
            }
        }
    }
}

// ---------------- segmented mean-pool (batch_ids sorted) ----------------
#define PCHUNK 512
__global__ __launch_bounds__(256)
void pool_kernel(const bf16* __restrict__ h, const int* __restrict__ batch_ids,
                 float* __restrict__ pooled, float* __restrict__ cnt)
{
    const int n0 = blockIdx.x * PCHUNK;
    const int f = threadIdx.x;
    __shared__ int bid_l[PCHUNK];
    for (int i = f; i < PCHUNK; i += 256) {
        int n = n0 + i;
        bid_l[i] = (n < NN) ? batch_ids[n] : -1;
    }
    __syncthreads();
    const int nEnd = (NN - n0 < PCHUNK) ? (NN - n0) : PCHUNK;
    float s = 0.0f;
    int g = bid_l[0];
    int run = 0;
    for (int i = 0; i < nEnd; ++i) {
        int bg = bid_l[i];
        if (bg != g) {
            atomicAdd(&pooled[g * HIDD + f], s);
            if (f == 0) atomicAdd(&cnt[g], (float)run);
            s = 0.0f; run = 0; g = bg;
        }
        s += (float)h[(size_t)(n0 + i) * HIDD + f];
        run++;
    }
    if (run > 0) {
        atomicAdd(&pooled[g * HIDD + f], s);
        if (f == 0) atomicAdd(&cnt[g], (float)run);
    }
}

// ---------------- MLP head ----------------
__global__ __launch_bounds__(256)
void mlp_kernel(const float* __restrict__ pooled, const float* __restrict__ cnt,
                const float* __restrict__ pW1, const float* __restrict__ pb1,
                const float* __restrict__ pW2, const float* __restrict__ pb2,
                float* __restrict__ out)
{
    const int g = blockIdx.x;
    const int d = threadIdx.x;
    __shared__ float pn[HIDD];
    __shared__ float mid[HIDD];
    float c = fmaxf(cnt[g], 1.0f);
    pn[d] = pooled[g * HIDD + d] / c;
    __syncthreads();
    float s = pb1[d];
    for (int k = 0; k < HIDD; ++k) s = fmaf(pn[k], pW1[k * HIDD + d], s);
    mid[d] = fmaxf(s, 0.0f);
    __syncthreads();
    float s2 = pb2[d];
    for (int k = 0; k < HIDD; ++k) s2 = fmaf(mid[k], pW2[k * HIDD + d], s2);
    out[g * HIDD + d] = s2;
}

extern "C" void kernel_launch(void* const* d_in, const int* in_sizes, int n_in,
                              void* d_out, int out_size, void* d_ws, size_t ws_size,
                              hipStream_t stream)
{
    const int*   x_type    = (const int*)d_in[0];
    const int*   x_sub     = (const int*)d_in[1];
    const int*   edges     = (const int*)d_in[2];
    const int*   batch_ids = (const int*)d_in[3];
    const float* type_emb  = (const float*)d_in[5];
    const float* sub_emb   = (const float*)d_in[6];
    const float* W_rel0    = (const float*)d_in[7];
    const float* W_self0   = (const float*)d_in[8];
    const float* b0        = (const float*)d_in[9];
    const float* W_rel1    = (const float*)d_in[10];
    const float* W_self1   = (const float*)d_in[11];
    const float* b1        = (const float*)d_in[12];
    const float* pW1       = (const float*)d_in[13];
    const float* pb1       = (const float*)d_in[14];
    const float* pW2       = (const float*)d_in[15];
    const float* pb2       = (const float*)d_in[16];
    float* out = (float*)d_out;

    // workspace carve-up (~116 MB; proven budget >= ~207 MB)
    char* p = (char*)d_ws;
    auto carve = [&](size_t bytes) { char* q = p; p += (bytes + 255) & ~255ull; return q; };
    bf16*  hA     = (bf16*) carve((size_t)NN * HIDD * sizeof(bf16));     // 51.2 MB
    bf16*  hB     = (bf16*) carve((size_t)NN * HIDD * sizeof(bf16));     // 51.2 MB
    bf16*  Wcat0  = (bf16*) carve((size_t)HIDD * KTOT * sizeof(bf16));   // 0.92 MB
    bf16*  Wcat1  = (bf16*) carve((size_t)HIDD * KTOT * sizeof(bf16));
    float* invdeg = (float*)carve((size_t)NN * sizeof(float));
    int*   hist   = (int*)  carve((size_t)NKEY * sizeof(int));
    int*   offs   = (int*)  carve((size_t)NKEY * sizeof(int));
    int*   cursor = (int*)  carve((size_t)NKEY * sizeof(int));
    int*   bsum   = (int*)  carve(2048 * sizeof(int));
    int*   ssrc   = (int*)  carve((size_t)NEDGT * sizeof(int));
    float* pooled = (float*)carve((size_t)NGR * HIDD * sizeof(float));
    float* cnt    = (float*)carve((size_t)NGR * sizeof(float));

    hipMemsetAsync(hist, 0, (size_t)NKEY * sizeof(int), stream);
    hipMemsetAsync(pooled, 0, (size_t)NGR * HIDD * sizeof(float), stream);
    hipMemsetAsync(cnt, 0, (size_t)NGR * sizeof(float), stream);

    embed_kernel<<<NN, 256, 0, stream>>>(x_type, x_sub, type_emb, sub_emb, hA);

    const int NB0 = (NKEY + 2047) / 2048;  // 293
    hist_kernel<<<(NEDGT + 255) / 256, 256, 0, stream>>>(edges, hist);
    scan_l0<<<NB0, 256, 0, stream>>>(hist, offs, bsum, NKEY);
    scan_l1<<<1, 256, 0, stream>>>(bsum, NB0);
    scan_l2<<<(NKEY + 255) / 256, 256, 0, stream>>>(offs, cursor, bsum, NKEY);
    scatter_kernel<<<(NEDGT + 255) / 256, 256, 0, stream>>>(edges, cursor, ssrc);
    invdeg_kernel<<<(NN + 255) / 256, 256, 0, stream>>>(hist, invdeg);

    dim3 wgrid(7, 256);
    build_wcat<<<wgrid, 256, 0, stream>>>(W_rel0, W_self0, Wcat0);
    build_wcat<<<wgrid, 256, 0, stream>>>(W_rel1, W_self1, Wcat1);

    const int FGRID = (NN + FBM - 1) / FBM;   // 1563
    rgcn_fused<<<FGRID, 256, 0, stream>>>(hA, Wcat0, b0, invdeg, offs, cursor, ssrc, hB);
    rgcn_fused<<<FGRID, 256, 0, stream>>>(hB, Wcat1, b1, invdeg, offs, cursor, ssrc, hA);

    pool_kernel<<<(NN + PCHUNK - 1) / PCHUNK, 256, 0, stream>>>(hA, batch_ids, pooled, cnt);
    mlp_kernel<<<NGR, 256, 0, stream>>>(pooled, cnt, pW1, pb1, pW2, pb2, out);
}

// Round 5
// 996.737 us; speedup vs baseline: 1.4611x; 1.1359x over previous
//
#include <hip/hip_runtime.h>

#define NN    100000   // nodes
#define NEDGE 100000   // edges per relation
#define NRELS 6
#define HIDD  256
#define NGR   128      // graphs
#define NKEY  (NRELS * NN)        // 600000 (rel,tgt) keys
#define NEDGT (NRELS * NEDGE)     // 600000 edges total
#define KTOT  (7 * HIDD)          // 1792

#define FBM 64                    // rows per block (nodes)

typedef __bf16 bf16;
typedef __bf16 bf16x4 __attribute__((ext_vector_type(4)));
typedef __bf16 bf16x8 __attribute__((ext_vector_type(8)));
typedef float  f32x16 __attribute__((ext_vector_type(16)));

// ---------------- embed ----------------
__global__ __launch_bounds__(256)
void embed_kernel(const int* __restrict__ xt, const int* __restrict__ xs,
                  const float* __restrict__ temb, const float* __restrict__ semb,
                  bf16* __restrict__ h)
{
    int n = blockIdx.x;
    int f = threadIdx.x;
    float v;
    if (f < 128) v = temb[xt[n] * 128 + f];
    else         v = semb[xs[n] * 128 + (f - 128)];
    h[(size_t)n * HIDD + f] = (bf16)v;
}

// ================= CSR build (key = rel*NN + tgt) =================
__global__ __launch_bounds__(256)
void hist_kernel(const int* __restrict__ edges, int* __restrict__ hist)
{
    int i = blockIdx.x * 256 + threadIdx.x;
    if (i >= NEDGT) return;
    int r = i / NEDGE;
    int e = i - r * NEDGE;
    int t = edges[r * (2 * NEDGE) + NEDGE + e];
    atomicAdd(&hist[r * NN + t], 1);
}

__global__ __launch_bounds__(256)
void scan_l0(const int* __restrict__ in, int* __restrict__ out, int* __restrict__ bsum, int n)
{
    __shared__ int sdata[256];
    const int t = threadIdx.x;
    const int base = blockIdx.x * 2048 + t * 8;
    int v[8]; int s = 0;
#pragma unroll
    for (int i = 0; i < 8; ++i) {
        int idx = base + i;
        int x = (idx < n) ? in[idx] : 0;
        v[i] = s; s += x;
    }
    sdata[t] = s;
    __syncthreads();
    for (int off = 1; off < 256; off <<= 1) {
        int y = (t >= off) ? sdata[t - off] : 0;
        __syncthreads();
        sdata[t] += y;
        __syncthreads();
    }
    int excl = sdata[t] - s;
#pragma unroll
    for (int i = 0; i < 8; ++i) {
        int idx = base + i;
        if (idx < n) out[idx] = excl + v[i];
    }
    if (t == 0) bsum[blockIdx.x] = sdata[255];
}

__global__ __launch_bounds__(256)
void scan_l1(int* __restrict__ bsum, int n)
{
    __shared__ int sdata[256];
    const int t = threadIdx.x;
    const int base = t * 8;
    int v[8]; int s = 0;
#pragma unroll
    for (int i = 0; i < 8; ++i) {
        int idx = base + i;
        int x = (idx < n) ? bsum[idx] : 0;
        v[i] = s; s += x;
    }
    sdata[t] = s;
    __syncthreads();
    for (int off = 1; off < 256; off <<= 1) {
        int y = (t >= off) ? sdata[t - off] : 0;
        __syncthreads();
        sdata[t] += y;
        __syncthreads();
    }
    int excl = sdata[t] - s;
#pragma unroll
    for (int i = 0; i < 8; ++i) {
        int idx = base + i;
        if (idx < n) bsum[idx] = excl + v[i];
    }
}

// adds block sums; writes cursor copy; one thread writes the NKEY sentinel
__global__ __launch_bounds__(256)
void scan_l2(int* __restrict__ offs, int* __restrict__ cursor, const int* __restrict__ bsum, int n)
{
    int idx = blockIdx.x * 256 + threadIdx.x;
    if (idx == 0) offs[NKEY] = NEDGT;
    if (idx >= n) return;
    int v = offs[idx] + bsum[idx >> 11];
    offs[idx] = v;
    cursor[idx] = v;
}

__global__ __launch_bounds__(256)
void scatter_kernel(const int* __restrict__ edges, int* __restrict__ cursor,
                    int* __restrict__ sorted_src, int* __restrict__ sorted_tgt)
{
    int i = blockIdx.x * 256 + threadIdx.x;
    if (i >= NEDGT) return;
    int r = i / NEDGE;
    int e = i - r * NEDGE;
    int s = edges[r * (2 * NEDGE) + e];
    int t = edges[r * (2 * NEDGE) + NEDGE + e];
    int pos = atomicAdd(&cursor[r * NN + t], 1);
    sorted_src[pos] = s;
    sorted_tgt[pos] = t;
}

__global__ __launch_bounds__(256)
void invdeg_kernel(const int* __restrict__ hist, float* __restrict__ invdeg)
{
    int t = blockIdx.x * 256 + threadIdx.x;
    if (t >= NN) return;
    int d = 0;
#pragma unroll
    for (int r = 0; r < NRELS; ++r) d += hist[r * NN + t];
    invdeg[t] = 1.0f / fmaxf((float)d, 1.0f);
}

// ---------------- Wcat[n][seg*256+k]: seg<6 -> W_rel[seg][k][n], seg6 -> W_self[k][n] ----------------
__global__ __launch_bounds__(256)
void build_wcat(const float* __restrict__ Wrel, const float* __restrict__ Wself,
                bf16* __restrict__ Wcat)
{
    int seg = blockIdx.x;
    int k = blockIdx.y;
    int n = threadIdx.x;
    float v = (seg < 6) ? Wrel[((size_t)seg << 16) + (k << 8) + n] : Wself[(k << 8) + n];
    Wcat[(size_t)n * KTOT + seg * 256 + k] = (bf16)v;
}

// ---------------- fused RGCN layer: out[t] = relu(sum_seg A_seg[t] @ Wcat_seg^T + b) ----------------
// grid ceil(NN/64), block 256 (4 waves). Wave w: output cols w*64..w*64+63, all 64 rows.
// A staged in LDS (XOR-swizzled 16B units); B fragments read DIRECTLY from global Wcat (L2-hot).
// A-build is edge-parallel: wave owns rows w*16..+16 = contiguous CSR edge range; edge meta
// prefetched 64-wide; h[src] rows loaded full-wave coalesced (512B), run-accumulated in regs.
__global__ __launch_bounds__(256, 4)
void rgcn_fused(const bf16* __restrict__ hin, const bf16* __restrict__ Wcat,
                const float* __restrict__ bias, const float* __restrict__ invdeg,
                const int* __restrict__ offs,
                const int* __restrict__ ssrc, const int* __restrict__ stgt,
                bf16* __restrict__ hout)
{
    const int m0 = blockIdx.x * FBM;
    const int tid = threadIdx.x;
    const int lane = tid & 63;
    const int w = tid >> 6;

    __shared__ __align__(16) bf16 As[FBM * HIDD];   // 32 KB

    f32x16 acc[2][2] = {};

    const int l31 = lane & 31;
    const int lhi = lane >> 5;          // k-octet selector (MFMA A/B frag)
    const int rbase_t = w * 16;         // this wave's row range in tile

    for (int seg = 0; seg < 7; ++seg) {
        __syncthreads();   // previous seg's MFMA reads of As complete

        // ---- zero this wave's As rows (16 rows x 256 bf16 = 8 KB) ----
#pragma unroll
        for (int z = 0; z < 8; ++z) {
            const int row = rbase_t + z * 2 + lhi;
            const int unit = row * 32 + (l31 ^ (row & 7));
            *(bf16x8*)&As[unit * 8] = (bf16x8)(bf16)0.0f;
        }

        if (seg == 6) {
            // ---- self segment: straight copy of h rows ----
#pragma unroll
            for (int z = 0; z < 8; ++z) {
                const int row = rbase_t + z * 2 + lhi;
                const int gr = m0 + row;
                if (gr < NN) {
                    bf16x8 u = *(const bf16x8*)(hin + ((size_t)gr << 8) + l31 * 8);
                    const int unit = row * 32 + (l31 ^ (row & 7));
                    *(bf16x8*)&As[unit * 8] = u;
                }
            }
        } else {
            // ---- edge-parallel aggregation for rows [m0+rbase_t, m0+rbase_t+16) ----
            const int gr0 = m0 + rbase_t;
            if (gr0 < NN) {
                const int rend = (gr0 + 16 < NN) ? (gr0 + 16) : NN;
                int st = offs[seg * NN + gr0];
                const int en = offs[seg * NN + rend];

                float a0 = 0.f, a1 = 0.f, a2 = 0.f, a3 = 0.f;
                int cur = -1;   // current local row being accumulated (wave-uniform)

                while (st < en) {
                    const int cnt = (en - st < 64) ? (en - st) : 64;
                    const int sv = (lane < cnt) ? ssrc[st + lane] : 0;
                    const int tv = (lane < cnt) ? stgt[st + lane] : 0;

                    int s_cur = __shfl(sv, 0);
                    bf16x4 u_cur = *(const bf16x4*)(hin + ((size_t)s_cur << 8) + lane * 4);
                    for (int i = 0; i < cnt; ++i) {
                        bf16x4 u_next;
                        if (i + 1 < cnt) {
                            const int s_n = __shfl(sv, i + 1);
                            u_next = *(const bf16x4*)(hin + ((size_t)s_n << 8) + lane * 4);
                        }
                        const int t = __shfl(tv, i) - m0;   // local row, wave-uniform
                        if (t != cur) {
                            if (cur >= 0) {
                                const float inv = invdeg[m0 + cur];
                                bf16x4 o;
                                o.x = (bf16)(a0 * inv); o.y = (bf16)(a1 * inv);
                                o.z = (bf16)(a2 * inv); o.w = (bf16)(a3 * inv);
                                const int unit = cur * 32 + ((lane >> 1) ^ (cur & 7));
                                *(bf16x4*)&As[unit * 8 + (lane & 1) * 4] = o;
                            }
                            cur = t; a0 = a1 = a2 = a3 = 0.f;
                        }
                        a0 += (float)u_cur.x; a1 += (float)u_cur.y;
                        a2 += (float)u_cur.z; a3 += (float)u_cur.w;
                        u_cur = u_next;
                    }
                    st += cnt;
                }
                if (cur >= 0) {
                    const float inv = invdeg[m0 + cur];
                    bf16x4 o;
                    o.x = (bf16)(a0 * inv); o.y = (bf16)(a1 * inv);
                    o.z = (bf16)(a2 * inv); o.w = (bf16)(a3 * inv);
                    const int unit = cur * 32 + ((lane >> 1) ^ (cur & 7));
                    *(bf16x4*)&As[unit * 8 + (lane & 1) * 4] = o;
                }
            }
        }

        __syncthreads();   // As ready for all waves

        // ---- MFMA: 16 k-steps of 16; B frags straight from global (L2-hot Wcat) ----
        const bf16* const wbase0 = Wcat + (size_t)(w * 64 + l31) * KTOT + seg * 256 + lhi * 8;
        const bf16* const wbase1 = wbase0 + (size_t)32 * KTOT;
#pragma unroll
        for (int step = 0; step < 16; ++step) {
            bf16x8 bfr0 = *(const bf16x8*)(wbase0 + step * 16);
            bf16x8 bfr1 = *(const bf16x8*)(wbase1 + step * 16);
            const int ku = step * 2 + lhi;
            bf16x8 afr[2];
#pragma unroll
            for (int rt = 0; rt < 2; ++rt) {
                const int row = rt * 32 + l31;
                const int u = row * 32 + (ku ^ (row & 7));
                afr[rt] = *(const bf16x8*)&As[u * 8];
            }
            acc[0][0] = __builtin_amdgcn_mfma_f32_32x32x16_bf16(afr[0], bfr0, acc[0][0], 0, 0, 0);
            acc[0][1] = __builtin_amdgcn_mfma_f32_32x32x16_bf16(afr[0], bfr1, acc[0][1], 0, 0, 0);
            acc[1][0] = __builtin_amdgcn_mfma_f32_32x32x16_bf16(afr[1], bfr0, acc[1][0], 0, 0, 0);
            acc[1][1] = __builtin_amdgcn_mfma_f32_32x32x16_bf16(afr[1], bfr1, acc[1][1], 0, 0, 0);
        }
    }

    // ---- epilogue: C col = lane&31 (+ct*32+w*64), row = (reg&3) + 8*(reg>>2) + 4*(lane>>5) ----
    float bcol[2];
#pragma unroll
    for (int ct = 0; ct < 2; ++ct) bcol[ct] = bias[w * 64 + ct * 32 + l31];
#pragma unroll
    for (int rt = 0; rt < 2; ++rt) {
#pragma unroll
        for (int reg = 0; reg < 16; ++reg) {
            const int row = m0 + rt * 32 + (reg & 3) + 8 * (reg >> 2) + 4 * lhi;
            if (row < NN) {
#pragma unroll
                for (int ct = 0; ct < 2; ++ct) {
                    const int col = w * 64 + ct * 32 + l31;
                    float v = acc[rt][ct][reg] + bcol[ct];
                    hout[((size_t)row << 8) + col] = (bf16)fmaxf(v, 0.0f);
                }
            }
        }
    }
}

// ---------------- segmented mean-pool (batch_ids sorted) ----------------
#define PCHUNK 512
__global__ __launch_bounds__(256)
void pool_kernel(const bf16* __restrict__ h, const int* __restrict__ batch_ids,
                 float* __restrict__ pooled, float* __restrict__ cnt)
{
    const int n0 = blockIdx.x * PCHUNK;
    const int f = threadIdx.x;
    __shared__ int bid_l[PCHUNK];
    for (int i = f; i < PCHUNK; i += 256) {
        int n = n0 + i;
        bid_l[i] = (n < NN) ? batch_ids[n] : -1;
    }
    __syncthreads();
    const int nEnd = (NN - n0 < PCHUNK) ? (NN - n0) : PCHUNK;
    float s = 0.0f;
    int g = bid_l[0];
    int run = 0;
    for (int i = 0; i < nEnd; ++i) {
        int bg = bid_l[i];
        if (bg != g) {
            atomicAdd(&pooled[g * HIDD + f], s);
            if (f == 0) atomicAdd(&cnt[g], (float)run);
            s = 0.0f; run = 0; g = bg;
        }
        s += (float)h[(size_t)(n0 + i) * HIDD + f];
        run++;
    }
    if (run > 0) {
        atomicAdd(&pooled[g * HIDD + f], s);
        if (f == 0) atomicAdd(&cnt[g], (float)run);
    }
}

// ---------------- MLP head ----------------
__global__ __launch_bounds__(256)
void mlp_kernel(const float* __restrict__ pooled, const float* __restrict__ cnt,
                const float* __restrict__ pW1, const float* __restrict__ pb1,
                const float* __restrict__ pW2, const float* __restrict__ pb2,
                float* __restrict__ out)
{
    const int g = blockIdx.x;
    const int d = threadIdx.x;
    __shared__ float pn[HIDD];
    __shared__ float mid[HIDD];
    float c = fmaxf(cnt[g], 1.0f);
    pn[d] = pooled[g * HIDD + d] / c;
    __syncthreads();
    float s = pb1[d];
    for (int k = 0; k < HIDD; ++k) s = fmaf(pn[k], pW1[k * HIDD + d], s);
    mid[d] = fmaxf(s, 0.0f);
    __syncthreads();
    float s2 = pb2[d];
    for (int k = 0; k < HIDD; ++k) s2 = fmaf(mid[k], pW2[k * HIDD + d], s2);
    out[g * HIDD + d] = s2;
}

extern "C" void kernel_launch(void* const* d_in, const int* in_sizes, int n_in,
                              void* d_out, int out_size, void* d_ws, size_t ws_size,
                              hipStream_t stream)
{
    const int*   x_type    = (const int*)d_in[0];
    const int*   x_sub     = (const int*)d_in[1];
    const int*   edges     = (const int*)d_in[2];
    const int*   batch_ids = (const int*)d_in[3];
    const float* type_emb  = (const float*)d_in[5];
    const float* sub_emb   = (const float*)d_in[6];
    const float* W_rel0    = (const float*)d_in[7];
    const float* W_self0   = (const float*)d_in[8];
    const float* b0        = (const float*)d_in[9];
    const float* W_rel1    = (const float*)d_in[10];
    const float* W_self1   = (const float*)d_in[11];
    const float* b1        = (const float*)d_in[12];
    const float* pW1       = (const float*)d_in[13];
    const float* pb1       = (const float*)d_in[14];
    const float* pW2       = (const float*)d_in[15];
    const float* pb2       = (const float*)d_in[16];
    float* out = (float*)d_out;

    // workspace carve-up (~121 MB)
    char* p = (char*)d_ws;
    auto carve = [&](size_t bytes) { char* q = p; p += (bytes + 255) & ~255ull; return q; };
    bf16*  hA     = (bf16*) carve((size_t)NN * HIDD * sizeof(bf16));     // 51.2 MB
    bf16*  hB     = (bf16*) carve((size_t)NN * HIDD * sizeof(bf16));     // 51.2 MB
    bf16*  Wcat0  = (bf16*) carve((size_t)HIDD * KTOT * sizeof(bf16));   // 0.92 MB
    bf16*  Wcat1  = (bf16*) carve((size_t)HIDD * KTOT * sizeof(bf16));
    float* invdeg = (float*)carve((size_t)NN * sizeof(float));
    int*   hist   = (int*)  carve((size_t)NKEY * sizeof(int));
    int*   offs   = (int*)  carve((size_t)(NKEY + 1) * sizeof(int));
    int*   cursor = (int*)  carve((size_t)NKEY * sizeof(int));
    int*   bsum   = (int*)  carve(2048 * sizeof(int));
    int*   ssrc   = (int*)  carve((size_t)NEDGT * sizeof(int));
    int*   stgt   = (int*)  carve((size_t)NEDGT * sizeof(int));
    float* pooled = (float*)carve((size_t)NGR * HIDD * sizeof(float));
    float* cnt    = (float*)carve((size_t)NGR * sizeof(float));

    hipMemsetAsync(hist, 0, (size_t)NKEY * sizeof(int), stream);
    hipMemsetAsync(pooled, 0, (size_t)NGR * HIDD * sizeof(float), stream);
    hipMemsetAsync(cnt, 0, (size_t)NGR * sizeof(float), stream);

    embed_kernel<<<NN, 256, 0, stream>>>(x_type, x_sub, type_emb, sub_emb, hA);

    const int NB0 = (NKEY + 2047) / 2048;  // 293
    hist_kernel<<<(NEDGT + 255) / 256, 256, 0, stream>>>(edges, hist);
    scan_l0<<<NB0, 256, 0, stream>>>(hist, offs, bsum, NKEY);
    scan_l1<<<1, 256, 0, stream>>>(bsum, NB0);
    scan_l2<<<(NKEY + 255) / 256, 256, 0, stream>>>(offs, cursor, bsum, NKEY);
    scatter_kernel<<<(NEDGT + 255) / 256, 256, 0, stream>>>(edges, cursor, ssrc, stgt);
    invdeg_kernel<<<(NN + 255) / 256, 256, 0, stream>>>(hist, invdeg);

    dim3 wgrid(7, 256);
    build_wcat<<<wgrid, 256, 0, stream>>>(W_rel0, W_self0, Wcat0);
    build_wcat<<<wgrid, 256, 0, stream>>>(W_rel1, W_self1, Wcat1);

    const int FGRID = (NN + FBM - 1) / FBM;   // 1563
    rgcn_fused<<<FGRID, 256, 0, stream>>>(hA, Wcat0, b0, invdeg, offs, ssrc, stgt, hB);
    rgcn_fused<<<FGRID, 256, 0, stream>>>(hB, Wcat1, b1, invdeg, offs, ssrc, stgt, hA);

    pool_kernel<<<(NN + PCHUNK - 1) / PCHUNK, 256, 0, stream>>>(hA, batch_ids, pooled, cnt);
    mlp_kernel<<<NGR, 256, 0, stream>>>(pooled, cnt, pW1, pb1, pW2, pb2, out);
}